// Round 1
// baseline (120.807 us; speedup 1.0000x reference)
//
#include <hip/hip_runtime.h>

// Problem constants
#define Bc  32
#define Nc  16
#define Tc  64
#define Hc  256
#define NTc 1024   // N*T

typedef unsigned short u16;
using v8s = __attribute__((ext_vector_type(8))) short;   // 8 bf16 = 4 VGPRs (MFMA A/B frag)
using v4f = __attribute__((ext_vector_type(4))) float;   // MFMA C/D frag

// fp32 -> bf16 round-to-nearest-even (bit manip; inputs finite)
static __device__ __forceinline__ u16 f2bf(float x) {
    unsigned u = __float_as_uint(x);
    unsigned r = u + 0x7fffu + ((u >> 16) & 1u);
    return (u16)(r >> 16);
}
static __device__ __forceinline__ float bf2f(u16 h) {
    return __uint_as_float(((unsigned)h) << 16);
}

// ---------------------------------------------------------------------------
// Prep kernel, 160 blocks (unchanged, known-good):
//  blocks [0,128): MT[b,h,t] = bf16( (1/16) * sum_i neigh[b,i,t,h] )
//  blocks [128,160): node_hi/node_lo[b,t,h] bf16 split of node; zero Wsum.
// ---------------------------------------------------------------------------
__global__ __launch_bounds__(256) void prep_kernel(const float* __restrict__ neigh,
                                                   const float* __restrict__ node,
                                                   u16* __restrict__ MT,
                                                   u16* __restrict__ NH,
                                                   u16* __restrict__ NL,
                                                   float* __restrict__ Wsum) {
    __shared__ float Ls[64][68];
    int bk = blockIdx.x, tid = threadIdx.x;

    if (bk < 128) {
        int b = bk >> 2, h0 = (bk & 3) << 6;
#pragma unroll
        for (int rep = 0; rep < 4; rep++) {
            int idx = rep * 256 + tid;
            int t = idx >> 4, c4 = idx & 15;
            const float4* p = (const float4*)(neigh + ((size_t)b * Nc * Tc + t) * Hc + h0) + c4;
            float4 a = make_float4(0.f, 0.f, 0.f, 0.f);
#pragma unroll
            for (int i = 0; i < Nc; i++) {
                float4 v = p[(size_t)i * (Tc * Hc / 4)];
                a.x += v.x; a.y += v.y; a.z += v.z; a.w += v.w;
            }
            const float r = 1.0f / 16.0f;
            Ls[t][c4 * 4 + 0] = a.x * r;
            Ls[t][c4 * 4 + 1] = a.y * r;
            Ls[t][c4 * 4 + 2] = a.z * r;
            Ls[t][c4 * 4 + 3] = a.w * r;
        }
        __syncthreads();
        // transpose-write bf16: MT[b][h0+h][t]
#pragma unroll
        for (int rep = 0; rep < 4; rep++) {
            int idx = rep * 256 + tid;
            int h = idx >> 4, t4 = idx & 15;
            ushort4 o;
            o.x = f2bf(Ls[t4 * 4 + 0][h]);
            o.y = f2bf(Ls[t4 * 4 + 1][h]);
            o.z = f2bf(Ls[t4 * 4 + 2][h]);
            o.w = f2bf(Ls[t4 * 4 + 3][h]);
            *(ushort4*)(MT + ((size_t)b * Hc + h0 + h) * Tc + t4 * 4) = o;
        }
    } else {
        int b = bk - 128;
#pragma unroll
        for (int rep = 0; rep < 16; rep++) {
            int idx = rep * 256 + tid;          // over 4096 float4 = 64x256 floats
            int t = idx >> 6, c4 = idx & 63;
            size_t off = ((size_t)b * Tc + t) * Hc + c4 * 4;
            float4 v = *(const float4*)(node + off);
            ushort4 hs, ls;
            hs.x = f2bf(v.x); ls.x = f2bf(v.x - bf2f(hs.x));
            hs.y = f2bf(v.y); ls.y = f2bf(v.y - bf2f(hs.y));
            hs.z = f2bf(v.z); ls.z = f2bf(v.z - bf2f(hs.z));
            hs.w = f2bf(v.w); ls.w = f2bf(v.w - bf2f(hs.w));
            *(ushort4*)(NH + off) = hs;
            *(ushort4*)(NL + off) = ls;
        }
        if (tid < 64) Wsum[b * 64 + tid] = 0.f;
    }
}

// ---------------------------------------------------------------------------
// Fused MFMA kernel v2: barrier-free register-fragment version.
// Block = (b, i), 4 waves; wave w owns q-rows w*16..w*16+15.
// Phase A: each lane loads its own A-row slice of X directly from global
//   (2 x float4 per K-step), converts to bf16 hi/lo in registers; B-frags
//   (NH/NL) loaded as aligned v8s straight from global (L2-resident, shared
//   by 16 blocks per b). No LDS staging, no barriers in the K-loop.
// Softmax in C-layout registers (wave-local rows); colsums -> Wsum atomics.
// P handoff through 9KB LDS (wave-local rows; one safety barrier).
// Phase B: B-frags (MT) loaded as v8s straight from global (L2-resident).
// Frag layouts (m89/m97-verified): A/B lane=(m|n)=lane&15, k=quad*8+j;
// C/D col=lane&15, row=quad*4+reg.
// ---------------------------------------------------------------------------
__global__ __launch_bounds__(256, 2) void fused_kernel(const float* __restrict__ neigh,
                                                       const u16* __restrict__ NH,
                                                       const u16* __restrict__ NL,
                                                       const int* __restrict__ nbr,
                                                       const u16* __restrict__ MT,
                                                       float* __restrict__ out,
                                                       float* __restrict__ Wsum) {
    __shared__ u16 Ph[64][72];   // P bf16 [q][t]

    int b  = blockIdx.x >> 4;
    int i  = blockIdx.x & 15;
    int q0 = i << 6;

    int tid  = threadIdx.x;
    int w    = tid >> 6;         // wave 0..3
    int lane = tid & 63;
    int quad = lane >> 4;
    int c    = lane & 15;

    // neighbors_number: int64 per reference; harness may upload int32.
    int nb = (nbr[1] == 0) ? nbr[2 * b] : nbr[b];
    float rscale = rsqrtf((float)nb);

    // this lane's A-row of X (row = w*16+c), k-offset quad*8
    const float* Xg  = neigh + ((size_t)(b * Nc + i) * Tc + w * 16 + c) * Hc;
    const u16*   NHg = NH + (size_t)b * Tc * Hc;
    const u16*   NLg = NL + (size_t)b * Tc * Hc;
    const u16*   MTg = MT + (size_t)b * Hc * Tc;

    v4f acc[4];
#pragma unroll
    for (int nt = 0; nt < 4; nt++)
#pragma unroll
        for (int rg = 0; rg < 4; rg++) acc[nt][rg] = 0.f;

    // ---- Phase A: S = X @ node^T, K=256 in register K-steps of 32 ----
#pragma unroll 2
    for (int k0 = 0; k0 < Hc; k0 += 32) {
        const float4* xp = (const float4*)(Xg + k0) + quad * 2;
        float4 x0 = xp[0];
        float4 x1 = xp[1];
        float xs[8] = {x0.x, x0.y, x0.z, x0.w, x1.x, x1.y, x1.z, x1.w};
        v8s ah, al;
#pragma unroll
        for (int j = 0; j < 8; j++) {
            u16 h = f2bf(xs[j]);
            ah[j] = (short)h;
            al[j] = (short)f2bf(xs[j] - bf2f(h));
        }
        size_t koff = (size_t)k0 + quad * 8;
#pragma unroll
        for (int nt = 0; nt < 4; nt++) {
            size_t roff = (size_t)(nt * 16 + c) * Hc + koff;
            v8s bh = *(const v8s*)(NHg + roff);
            v8s bl = *(const v8s*)(NLg + roff);
            acc[nt] = __builtin_amdgcn_mfma_f32_16x16x32_bf16(ah, bh, acc[nt], 0, 0, 0);
            acc[nt] = __builtin_amdgcn_mfma_f32_16x16x32_bf16(ah, bl, acc[nt], 0, 0, 0);
            acc[nt] = __builtin_amdgcn_mfma_f32_16x16x32_bf16(al, bh, acc[nt], 0, 0, 0);
        }
    }

    // ---- Softmax over t (C-layout: col = nt*16+c, row = w*16+quad*4+rg) ----
#pragma unroll
    for (int nt = 0; nt < 4; nt++)
#pragma unroll
        for (int rg = 0; rg < 4; rg++) acc[nt][rg] *= rscale;

#pragma unroll
    for (int rg = 0; rg < 4; rg++) {
        float m = fmaxf(fmaxf(acc[0][rg], acc[1][rg]), fmaxf(acc[2][rg], acc[3][rg]));
#pragma unroll
        for (int d = 1; d < 16; d <<= 1) m = fmaxf(m, __shfl_xor(m, d));
        float e0 = __expf(acc[0][rg] - m);
        float e1 = __expf(acc[1][rg] - m);
        float e2 = __expf(acc[2][rg] - m);
        float e3 = __expf(acc[3][rg] - m);
        float s = e0 + e1 + e2 + e3;
#pragma unroll
        for (int d = 1; d < 16; d <<= 1) s += __shfl_xor(s, d);
        float inv = 1.0f / s;
        acc[0][rg] = e0 * inv; acc[1][rg] = e1 * inv;
        acc[2][rg] = e2 * inv; acc[3][rg] = e3 * inv;
    }

    // Column sums for W: per lane partial over its 4 rows, reduce across
    // quads, one atomic per (b,t) per wave.
#pragma unroll
    for (int nt = 0; nt < 4; nt++) {
        float cs = acc[nt][0] + acc[nt][1] + acc[nt][2] + acc[nt][3];
        cs += __shfl_xor(cs, 16);
        cs += __shfl_xor(cs, 32);
        if (quad == 0) atomicAdd(&Wsum[b * Tc + nt * 16 + c], cs);
    }

    // P -> LDS as bf16 (row = w*16+quad*4+rg, col = nt*16+c); wave-local rows
#pragma unroll
    for (int nt = 0; nt < 4; nt++)
#pragma unroll
        for (int rg = 0; rg < 4; rg++)
            Ph[w * 16 + quad * 4 + rg][nt * 16 + c] = f2bf(acc[nt][rg]);

    __syncthreads();   // single barrier: P write->read ordering (safety)

    // ---- Phase B: out = P(64x64) @ M(64x256), bf16 MFMA, K=64 ----
    v8s pa0 = *(const v8s*)&Ph[w * 16 + c][quad * 8];
    v8s pa1 = *(const v8s*)&Ph[w * 16 + c][32 + quad * 8];

    float* ob = out + ((size_t)b * NTc + q0 + w * 16 + quad * 4) * Hc + c;

#pragma unroll 4
    for (int hc = 0; hc < 16; hc++) {
        const u16* mp = MTg + (size_t)(hc * 16 + c) * Tc + quad * 8;
        v8s b0 = *(const v8s*)mp;
        v8s b1 = *(const v8s*)(mp + 32);
        v4f oc;
#pragma unroll
        for (int rg = 0; rg < 4; rg++) oc[rg] = 0.f;
        oc = __builtin_amdgcn_mfma_f32_16x16x32_bf16(pa0, b0, oc, 0, 0, 0);
        oc = __builtin_amdgcn_mfma_f32_16x16x32_bf16(pa1, b1, oc, 0, 0, 0);
#pragma unroll
        for (int rg = 0; rg < 4; rg++)
            ob[(size_t)rg * Hc + hc * 16] = oc[rg];
    }
}

// ---------------------------------------------------------------------------
// W[b,i,t] = Wsum[b,t] / 16  (independent of i)
// ---------------------------------------------------------------------------
__global__ __launch_bounds__(256) void wexp_kernel(const float* __restrict__ Wsum,
                                                   float* __restrict__ Wout) {
    int idx = blockIdx.x * 256 + threadIdx.x;   // over B*N*T = 32768
    int b = idx >> 10;
    int t = idx & 63;
    Wout[idx] = Wsum[b * Tc + t] * (1.0f / 16.0f);
}

// ---------------------------------------------------------------------------
extern "C" void kernel_launch(void* const* d_in, const int* in_sizes, int n_in,
                              void* d_out, int out_size, void* d_ws, size_t ws_size,
                              hipStream_t stream) {
    const float* node  = (const float*)d_in[0];   // (B,T,H)
    const float* neigh = (const float*)d_in[1];   // (B,N,T,H)
    const int*   nbr   = (const int*)d_in[2];     // (B,) int32/int64 (detected)

    float* out = (float*)d_out;                   // (B,NT,H) then W (B,N,T)

    u16* MTw = (u16*)d_ws;                        // [B][H][T] bf16 transposed mean
    u16* NHw = MTw + (size_t)Bc * Hc * Tc;        // [B][T][H] bf16 node hi
    u16* NLw = NHw + (size_t)Bc * Tc * Hc;        // [B][T][H] bf16 node lo
    float* Ww = (float*)(NLw + (size_t)Bc * Tc * Hc);  // [B][T] fp32

    prep_kernel <<<160, 256, 0, stream>>>(neigh, node, MTw, NHw, NLw, Ww);
    fused_kernel<<<512, 256, 0, stream>>>(neigh, NHw, NLw, nbr, MTw, out, Ww);
    wexp_kernel <<<128, 256, 0, stream>>>(Ww, out + (size_t)Bc * NTc * Hc);
}

// Round 3
// 114.226 us; speedup vs baseline: 1.0576x; 1.0576x over previous
//
#include <hip/hip_runtime.h>

// Problem constants
#define Bc  32
#define Nc  16
#define Tc  64
#define Hc  256
#define NTc 1024   // N*T

typedef unsigned short u16;
using v8s = __attribute__((ext_vector_type(8))) short;   // 8 bf16 = 4 VGPRs (MFMA A/B frag)
using v4f = __attribute__((ext_vector_type(4))) float;   // MFMA C/D frag

// fp32 -> bf16 round-to-nearest-even (bit manip; inputs finite)
static __device__ __forceinline__ u16 f2bf(float x) {
    unsigned u = __float_as_uint(x);
    unsigned r = u + 0x7fffu + ((u >> 16) & 1u);
    return (u16)(r >> 16);
}
static __device__ __forceinline__ float bf2f(u16 h) {
    return __uint_as_float(((unsigned)h) << 16);
}

// ---------------------------------------------------------------------------
// Prep kernel, 288 blocks:
//  blocks [0,256): MT[b,h,t] = bf16( (1/16) * sum_i neigh[b,i,t,h] )
//    one (b, 64-h chunk, 32-t chunk) per block -> full-GPU BW on the 33.5MB
//    neigh read (was 128 blocks = half the CUs idle).
//  blocks [256,288): node hi/lo bf16 split; zero Wsum.
// ---------------------------------------------------------------------------
__global__ __launch_bounds__(256) void prep_kernel(const float* __restrict__ neigh,
                                                   const float* __restrict__ node,
                                                   u16* __restrict__ MT,
                                                   u16* __restrict__ NH,
                                                   u16* __restrict__ NL,
                                                   float* __restrict__ Wsum) {
    __shared__ float Ls[32][68];
    int bk = blockIdx.x, tid = threadIdx.x;

    if (bk < 256) {
        int b  = bk >> 3;
        int sub = bk & 7;
        int h0 = (sub & 3) << 6;    // 4 h-chunks of 64
        int t0 = (sub >> 2) << 5;   // 2 t-chunks of 32
#pragma unroll
        for (int rep = 0; rep < 2; rep++) {
            int idx = rep * 256 + tid;          // over 32t x 16 c4 = 512
            int t = idx >> 4, c4 = idx & 15;
            const float4* p = (const float4*)(neigh + ((size_t)b * Nc * Tc + t0 + t) * Hc + h0) + c4;
            float4 a = make_float4(0.f, 0.f, 0.f, 0.f);
#pragma unroll
            for (int i = 0; i < Nc; i++) {
                float4 v = p[(size_t)i * (Tc * Hc / 4)];
                a.x += v.x; a.y += v.y; a.z += v.z; a.w += v.w;
            }
            const float r = 1.0f / 16.0f;
            Ls[t][c4 * 4 + 0] = a.x * r;
            Ls[t][c4 * 4 + 1] = a.y * r;
            Ls[t][c4 * 4 + 2] = a.z * r;
            Ls[t][c4 * 4 + 3] = a.w * r;
        }
        __syncthreads();
        // transpose-write bf16: MT[b][h0+h][t0 + 0..31]
#pragma unroll
        for (int rep = 0; rep < 2; rep++) {
            int idx = rep * 256 + tid;          // over 64h x 8 t4-groups = 512
            int h = idx >> 3, t4 = idx & 7;
            ushort4 o;
            o.x = f2bf(Ls[t4 * 4 + 0][h]);
            o.y = f2bf(Ls[t4 * 4 + 1][h]);
            o.z = f2bf(Ls[t4 * 4 + 2][h]);
            o.w = f2bf(Ls[t4 * 4 + 3][h]);
            *(ushort4*)(MT + ((size_t)b * Hc + h0 + h) * Tc + t0 + t4 * 4) = o;
        }
    } else {
        int b = bk - 256;
#pragma unroll
        for (int rep = 0; rep < 16; rep++) {
            int idx = rep * 256 + tid;          // over 4096 float4 = 64x256 floats
            int t = idx >> 6, c4 = idx & 63;
            size_t off = ((size_t)b * Tc + t) * Hc + c4 * 4;
            float4 v = *(const float4*)(node + off);
            ushort4 hs, ls;
            hs.x = f2bf(v.x); ls.x = f2bf(v.x - bf2f(hs.x));
            hs.y = f2bf(v.y); ls.y = f2bf(v.y - bf2f(hs.y));
            hs.z = f2bf(v.z); ls.z = f2bf(v.z - bf2f(hs.z));
            hs.w = f2bf(v.w); ls.w = f2bf(v.w - bf2f(hs.w));
            *(ushort4*)(NH + off) = hs;
            *(ushort4*)(NL + off) = ls;
        }
        if (tid < 64) Wsum[b * 64 + tid] = 0.f;
    }
}

// ---------------------------------------------------------------------------
// Fused MFMA kernel v3: hybrid of v1 (LDS for fragment-transposed operands)
// and v2 (per-lane X streaming, barrier-free K-loop, atomic Wsum).
//  - NH/NL staged ONCE as full [64][256] hi/lo tiles (64KB LDS, coalesced,
//    XOR-swizzled granules) -> K-loop has no barriers.
//  - X (neigh row) loaded per-lane from global: lane streams its OWN row in
//    32B chunks (this is the HBM re-read; contiguous per lane).
//  - Phase B MT staged once into reused NSh space, T14 split: global->regs
//    issued before softmax, regs->LDS after barrier.
//  - 3 barriers total (was 13). P handoff stays in LDS (ordered by the MT
//    barriers). Wsum via global atomics.
// Swizzle (T2, both-sides involution): 16B granule g at row r stored at
// g ^ (r&7). Balances fragment reads (16 rows x same col window) across all
// 8 bank-slots; unswizzled would serialize 2x.
// Frag layouts (m89/m97-verified): A/B lane=(m|n)=lane&15, k=quad*8+j;
// C/D col=lane&15, row=quad*4+reg.
// ---------------------------------------------------------------------------
__global__ __launch_bounds__(256, 2) void fused_kernel(const float* __restrict__ neigh,
                                                       const u16* __restrict__ NH,
                                                       const u16* __restrict__ NL,
                                                       const int* __restrict__ nbr,
                                                       const u16* __restrict__ MT,
                                                       float* __restrict__ out,
                                                       float* __restrict__ Wsum) {
    __shared__ u16 NSh[64 * 256];   // node hi tile, swizzled; reused for MT in Phase B
    __shared__ u16 NSl[64 * 256];   // node lo tile, swizzled
    __shared__ u16 Ph[64][72];      // P bf16 [q][t]

    int b  = blockIdx.x >> 4;
    int i  = blockIdx.x & 15;
    int q0 = i << 6;

    int tid  = threadIdx.x;
    int w    = tid >> 6;         // wave 0..3
    int lane = tid & 63;
    int quad = lane >> 4;
    int c    = lane & 15;
    int r3   = c & 7;

    // neighbors_number: int64 per reference; harness may upload int32.
    int nb = (nbr[1] == 0) ? nbr[2 * b] : nbr[b];
    float rscale = rsqrtf((float)nb);

    const u16* NHg = NH + (size_t)b * Tc * Hc;
    const u16* NLg = NL + (size_t)b * Tc * Hc;
    const u16* MTg = MT + (size_t)b * Hc * Tc;
    // this lane's A-row of X (row = w*16+c)
    const float* XgL = neigh + ((size_t)(b * Nc + i) * Tc + w * 16 + c) * Hc;

    // ---- stage node hi/lo tiles (coalesced copy, swizzled granule) ----
#pragma unroll
    for (int rep = 0; rep < 8; rep++) {
        int idx = rep * 256 + tid;              // 2048 16B-chunks per array
        int row = idx >> 5, g = idx & 31;
        int dst = row * 256 + ((g ^ (row & 7)) << 3);
        *(uint4*)&NSh[dst] = *(const uint4*)(NHg + row * 256 + g * 8);
        *(uint4*)&NSl[dst] = *(const uint4*)(NLg + row * 256 + g * 8);
    }
    __syncthreads();

    v4f acc[4];
#pragma unroll
    for (int nt = 0; nt < 4; nt++)
#pragma unroll
        for (int rg = 0; rg < 4; rg++) acc[nt][rg] = 0.f;

    // ---- Phase A: S = X @ node^T, K=256, no barriers ----
#pragma unroll 2
    for (int k0 = 0; k0 < Hc; k0 += 32) {
        float4 x0 = *(const float4*)(XgL + k0 + quad * 8);
        float4 x1 = *(const float4*)(XgL + k0 + quad * 8 + 4);
        float xs[8] = {x0.x, x0.y, x0.z, x0.w, x1.x, x1.y, x1.z, x1.w};
        v8s ah, al;
#pragma unroll
        for (int j = 0; j < 8; j++) {
            u16 h = f2bf(xs[j]);
            ah[j] = (short)h;
            al[j] = (short)f2bf(xs[j] - bf2f(h));
        }
        int gk = (k0 >> 3) + quad;
#pragma unroll
        for (int nt = 0; nt < 4; nt++) {
            int off = (nt * 16 + c) * 256 + ((gk ^ r3) << 3);
            v8s bh = *(const v8s*)&NSh[off];
            v8s bl = *(const v8s*)&NSl[off];
            acc[nt] = __builtin_amdgcn_mfma_f32_16x16x32_bf16(ah, bh, acc[nt], 0, 0, 0);
            acc[nt] = __builtin_amdgcn_mfma_f32_16x16x32_bf16(ah, bl, acc[nt], 0, 0, 0);
            acc[nt] = __builtin_amdgcn_mfma_f32_16x16x32_bf16(al, bh, acc[nt], 0, 0, 0);
        }
    }

    // ---- T14 async split: issue MT global->reg loads, hide under softmax ----
    uint4 mt[8];
#pragma unroll
    for (int rep = 0; rep < 8; rep++) {
        int idx = rep * 256 + tid;              // 2048 16B-chunks (256 rows x 8)
        int row = idx >> 3, g = idx & 7;
        mt[rep] = *(const uint4*)(MTg + row * 64 + g * 8);
    }

    // ---- Softmax over t (C-layout: col = nt*16+c, row = w*16+quad*4+rg) ----
#pragma unroll
    for (int nt = 0; nt < 4; nt++)
#pragma unroll
        for (int rg = 0; rg < 4; rg++) acc[nt][rg] *= rscale;

#pragma unroll
    for (int rg = 0; rg < 4; rg++) {
        float m = fmaxf(fmaxf(acc[0][rg], acc[1][rg]), fmaxf(acc[2][rg], acc[3][rg]));
#pragma unroll
        for (int d = 1; d < 16; d <<= 1) m = fmaxf(m, __shfl_xor(m, d));
        float e0 = __expf(acc[0][rg] - m);
        float e1 = __expf(acc[1][rg] - m);
        float e2 = __expf(acc[2][rg] - m);
        float e3 = __expf(acc[3][rg] - m);
        float s = e0 + e1 + e2 + e3;
#pragma unroll
        for (int d = 1; d < 16; d <<= 1) s += __shfl_xor(s, d);
        float inv = 1.0f / s;
        acc[0][rg] = e0 * inv; acc[1][rg] = e1 * inv;
        acc[2][rg] = e2 * inv; acc[3][rg] = e3 * inv;
    }

    // Column sums for W: reduce across quads, one atomic per (b,t) per wave.
#pragma unroll
    for (int nt = 0; nt < 4; nt++) {
        float cs = acc[nt][0] + acc[nt][1] + acc[nt][2] + acc[nt][3];
        cs += __shfl_xor(cs, 16);
        cs += __shfl_xor(cs, 32);
        if (quad == 0) atomicAdd(&Wsum[b * Tc + nt * 16 + c], cs);
    }

    // P -> LDS as bf16 (row = w*16+quad*4+rg, col = nt*16+c); wave-local rows
#pragma unroll
    for (int nt = 0; nt < 4; nt++)
#pragma unroll
        for (int rg = 0; rg < 4; rg++)
            Ph[w * 16 + quad * 4 + rg][nt * 16 + c] = f2bf(acc[nt][rg]);

    __syncthreads();   // all Phase-A NSh/NSl reads done -> safe to overwrite

    // ---- MT regs -> LDS (swizzled), reusing NSh space ----
#pragma unroll
    for (int rep = 0; rep < 8; rep++) {
        int idx = rep * 256 + tid;
        int row = idx >> 3, g = idx & 7;
        *(uint4*)&NSh[row * 64 + ((g ^ (row & 7)) << 3)] = mt[rep];
    }
    __syncthreads();

    // ---- Phase B: out = P(64x64) @ M(64x256), K=64 ----
    v8s pa0 = *(const v8s*)&Ph[w * 16 + c][quad * 8];
    v8s pa1 = *(const v8s*)&Ph[w * 16 + c][32 + quad * 8];

    float* ob = out + ((size_t)b * NTc + q0 + w * 16 + quad * 4) * Hc + c;

#pragma unroll 4
    for (int hc = 0; hc < 16; hc++) {
        int rowm = hc * 16 + c;
        v8s b0 = *(const v8s*)&NSh[rowm * 64 + ((quad ^ r3) << 3)];
        v8s b1 = *(const v8s*)&NSh[rowm * 64 + (((4 + quad) ^ r3) << 3)];
        v4f oc;
#pragma unroll
        for (int rg = 0; rg < 4; rg++) oc[rg] = 0.f;
        oc = __builtin_amdgcn_mfma_f32_16x16x32_bf16(pa0, b0, oc, 0, 0, 0);
        oc = __builtin_amdgcn_mfma_f32_16x16x32_bf16(pa1, b1, oc, 0, 0, 0);
#pragma unroll
        for (int rg = 0; rg < 4; rg++)
            ob[(size_t)rg * Hc + hc * 16] = oc[rg];
    }
}

// ---------------------------------------------------------------------------
// W[b,i,t] = Wsum[b,t] / 16  (independent of i)
// ---------------------------------------------------------------------------
__global__ __launch_bounds__(256) void wexp_kernel(const float* __restrict__ Wsum,
                                                   float* __restrict__ Wout) {
    int idx = blockIdx.x * 256 + threadIdx.x;   // over B*N*T = 32768
    int b = idx >> 10;
    int t = idx & 63;
    Wout[idx] = Wsum[b * Tc + t] * (1.0f / 16.0f);
}

// ---------------------------------------------------------------------------
extern "C" void kernel_launch(void* const* d_in, const int* in_sizes, int n_in,
                              void* d_out, int out_size, void* d_ws, size_t ws_size,
                              hipStream_t stream) {
    const float* node  = (const float*)d_in[0];   // (B,T,H)
    const float* neigh = (const float*)d_in[1];   // (B,N,T,H)
    const int*   nbr   = (const int*)d_in[2];     // (B,) int32/int64 (detected)

    float* out = (float*)d_out;                   // (B,NT,H) then W (B,N,T)

    u16* MTw = (u16*)d_ws;                        // [B][H][T] bf16 transposed mean
    u16* NHw = MTw + (size_t)Bc * Hc * Tc;        // [B][T][H] bf16 node hi
    u16* NLw = NHw + (size_t)Bc * Tc * Hc;        // [B][T][H] bf16 node lo
    float* Ww = (float*)(NLw + (size_t)Bc * Tc * Hc);  // [B][T] fp32

    prep_kernel <<<288, 256, 0, stream>>>(neigh, node, MTw, NHw, NLw, Ww);
    fused_kernel<<<512, 256, 0, stream>>>(neigh, NHw, NLw, nbr, MTw, out, Ww);
    wexp_kernel <<<128, 256, 0, stream>>>(Ww, out + (size_t)Bc * NTc * Hc);
}

// Round 5
// 104.740 us; speedup vs baseline: 1.1534x; 1.0906x over previous
//
#include <hip/hip_runtime.h>

// Problem constants
#define Bc  32
#define Nc  16
#define Tc  64
#define Hc  256
#define NTc 1024   // N*T

typedef unsigned short u16;
using v8s = __attribute__((ext_vector_type(8))) short;   // 8 bf16 = 4 VGPRs (MFMA A/B frag)
using v4f = __attribute__((ext_vector_type(4))) float;   // MFMA C/D frag

// fp32 -> bf16 round-to-nearest-even (bit manip; inputs finite)
static __device__ __forceinline__ u16 f2bf(float x) {
    unsigned u = __float_as_uint(x);
    unsigned r = u + 0x7fffu + ((u >> 16) & 1u);
    return (u16)(r >> 16);
}
static __device__ __forceinline__ float bf2f(u16 h) {
    return __uint_as_float(((unsigned)h) << 16);
}

// ---------------------------------------------------------------------------
// Prep kernel, 256 blocks — M only (v3-proven code path):
//  MT[b,h,t] = bf16( (1/16) * sum_i neigh[b,i,t,h] )
//  one (b, 64-h chunk, 32-t chunk) per block -> full-GPU BW on the 33.5MB
//  neigh read.
// ---------------------------------------------------------------------------
__global__ __launch_bounds__(256) void prep_kernel(const float* __restrict__ neigh,
                                                   u16* __restrict__ MT) {
    __shared__ float Ls[32][68];
    int bk = blockIdx.x, tid = threadIdx.x;

    int b  = bk >> 3;
    int sub = bk & 7;
    int h0 = (sub & 3) << 6;    // 4 h-chunks of 64
    int t0 = (sub >> 2) << 5;   // 2 t-chunks of 32
#pragma unroll
    for (int rep = 0; rep < 2; rep++) {
        int idx = rep * 256 + tid;          // over 32t x 16 c4 = 512
        int t = idx >> 4, c4 = idx & 15;
        const float4* p = (const float4*)(neigh + ((size_t)b * Nc * Tc + t0 + t) * Hc + h0) + c4;
        float4 a = make_float4(0.f, 0.f, 0.f, 0.f);
#pragma unroll
        for (int i = 0; i < Nc; i++) {
            float4 v = p[(size_t)i * (Tc * Hc / 4)];
            a.x += v.x; a.y += v.y; a.z += v.z; a.w += v.w;
        }
        const float r = 1.0f / 16.0f;
        Ls[t][c4 * 4 + 0] = a.x * r;
        Ls[t][c4 * 4 + 1] = a.y * r;
        Ls[t][c4 * 4 + 2] = a.z * r;
        Ls[t][c4 * 4 + 3] = a.w * r;
    }
    __syncthreads();
    // transpose-write bf16: MT[b][h0+h][t0 + 0..31]
#pragma unroll
    for (int rep = 0; rep < 2; rep++) {
        int idx = rep * 256 + tid;          // over 64h x 8 t4-groups = 512
        int h = idx >> 3, t4 = idx & 7;
        ushort4 o;
        o.x = f2bf(Ls[t4 * 4 + 0][h]);
        o.y = f2bf(Ls[t4 * 4 + 1][h]);
        o.z = f2bf(Ls[t4 * 4 + 2][h]);
        o.w = f2bf(Ls[t4 * 4 + 3][h]);
        *(ushort4*)(MT + ((size_t)b * Hc + h0 + h) * Tc + t0 + t4 * 4) = o;
    }
}

// ---------------------------------------------------------------------------
// Fused MFMA kernel (v0 structure, 107.7us-proven, with two local edits):
//  (1) node chunk staged from fp32 directly (hi/lo split in staging; kills
//      the NH/NL workspace round-trip). node[b]=64KB, L2-resident for the
//      16 sibling blocks.
//  (2) column sums stored to private Wpart[b][i][t] (no atomics, no init).
// Everything else identical to v0: chunked LDS pipeline, barriers, softmax,
// Phase B per-chunk MT staging.
// Frag layouts (m89/m97-verified): A/B lane=(m|n)=lane&15, k=quad*8+j;
// C/D col=lane&15, row=quad*4+reg.
// ---------------------------------------------------------------------------
__global__ __launch_bounds__(256, 2) void fused_kernel(const float* __restrict__ neigh,
                                                       const float* __restrict__ node,
                                                       const int* __restrict__ nbr,
                                                       const u16* __restrict__ MT,
                                                       float* __restrict__ out,
                                                       float* __restrict__ Wpart) {
    __shared__ u16 Xh[64][72];   // X hi (also reused as M-chunk stage in Phase B)
    __shared__ u16 Xl[64][72];   // X lo
    __shared__ u16 Nh[64][72];   // node hi chunk [t][k]
    __shared__ u16 Nl[64][72];   // node lo chunk
    __shared__ u16 Ph[64][72];   // P bf16 [q][t]
    __shared__ float Wtmp[256];

    int b  = blockIdx.x >> 4;
    int i  = blockIdx.x & 15;
    int q0 = i << 6;

    int tid  = threadIdx.x;
    int w    = tid >> 6;         // wave 0..3
    int lane = tid & 63;
    int quad = lane >> 4;
    int c    = lane & 15;

    // neighbors_number: int64 per reference; harness may upload int32.
    // Values in [1,16] so nbr[1]==0 <=> int64 (high word of elem 0).
    int nb = (nbr[1] == 0) ? nbr[2 * b] : nbr[b];
    float rscale = rsqrtf((float)nb);

    const float* Xg  = neigh + ((size_t)b * Nc * Tc + q0) * Hc;
    const float* Ng  = node + (size_t)b * Tc * Hc;
    const u16*   MTg = MT + (size_t)b * Hc * Tc;

    v4f acc[4];
#pragma unroll
    for (int nt = 0; nt < 4; nt++)
#pragma unroll
        for (int rg = 0; rg < 4; rg++) acc[nt][rg] = 0.f;

    // ---- Phase A: K=256 in chunks of 64 ----
    for (int k0 = 0; k0 < Hc; k0 += 64) {
        // stage X chunk (64q x 64k fp32 -> hi/lo bf16)
#pragma unroll
        for (int rep = 0; rep < 4; rep++) {
            int idx = rep * 256 + tid;
            int row = idx >> 4, c4 = idx & 15;
            float4 xv = *(const float4*)(Xg + (size_t)row * Hc + k0 + c4 * 4);
            ushort4 hs, ls;
            hs.x = f2bf(xv.x); ls.x = f2bf(xv.x - bf2f(hs.x));
            hs.y = f2bf(xv.y); ls.y = f2bf(xv.y - bf2f(hs.y));
            hs.z = f2bf(xv.z); ls.z = f2bf(xv.z - bf2f(hs.z));
            hs.w = f2bf(xv.w); ls.w = f2bf(xv.w - bf2f(hs.w));
            *(ushort4*)&Xh[row][c4 * 4] = hs;
            *(ushort4*)&Xl[row][c4 * 4] = ls;
        }
        // stage node chunk (fp32 -> hi/lo bf16; L2-resident source)
#pragma unroll
        for (int rep = 0; rep < 4; rep++) {
            int idx = rep * 256 + tid;
            int row = idx >> 4, c4 = idx & 15;
            float4 nv = *(const float4*)(Ng + (size_t)row * Hc + k0 + c4 * 4);
            ushort4 hs, ls;
            hs.x = f2bf(nv.x); ls.x = f2bf(nv.x - bf2f(hs.x));
            hs.y = f2bf(nv.y); ls.y = f2bf(nv.y - bf2f(hs.y));
            hs.z = f2bf(nv.z); ls.z = f2bf(nv.z - bf2f(hs.z));
            hs.w = f2bf(nv.w); ls.w = f2bf(nv.w - bf2f(hs.w));
            *(ushort4*)&Nh[row][c4 * 4] = hs;
            *(ushort4*)&Nl[row][c4 * 4] = ls;
        }
        __syncthreads();

#pragma unroll
        for (int ks = 0; ks < 64; ks += 32) {
            v8s ah = *(const v8s*)&Xh[w * 16 + c][ks + quad * 8];
            v8s al = *(const v8s*)&Xl[w * 16 + c][ks + quad * 8];
#pragma unroll
            for (int nt = 0; nt < 4; nt++) {
                v8s bh = *(const v8s*)&Nh[nt * 16 + c][ks + quad * 8];
                v8s bl = *(const v8s*)&Nl[nt * 16 + c][ks + quad * 8];
                acc[nt] = __builtin_amdgcn_mfma_f32_16x16x32_bf16(ah, bh, acc[nt], 0, 0, 0);
                acc[nt] = __builtin_amdgcn_mfma_f32_16x16x32_bf16(ah, bl, acc[nt], 0, 0, 0);
                acc[nt] = __builtin_amdgcn_mfma_f32_16x16x32_bf16(al, bh, acc[nt], 0, 0, 0);
            }
        }
        __syncthreads();
    }

    // ---- Softmax over t (C-layout: col = nt*16+c, row = w*16+quad*4+rg) ----
#pragma unroll
    for (int nt = 0; nt < 4; nt++)
#pragma unroll
        for (int rg = 0; rg < 4; rg++) acc[nt][rg] *= rscale;

#pragma unroll
    for (int rg = 0; rg < 4; rg++) {
        float m = fmaxf(fmaxf(acc[0][rg], acc[1][rg]), fmaxf(acc[2][rg], acc[3][rg]));
#pragma unroll
        for (int d = 1; d < 16; d <<= 1) m = fmaxf(m, __shfl_xor(m, d));
        float e0 = __expf(acc[0][rg] - m);
        float e1 = __expf(acc[1][rg] - m);
        float e2 = __expf(acc[2][rg] - m);
        float e3 = __expf(acc[3][rg] - m);
        float s = e0 + e1 + e2 + e3;
#pragma unroll
        for (int d = 1; d < 16; d <<= 1) s += __shfl_xor(s, d);
        float inv = 1.0f / s;
        acc[0][rg] = e0 * inv; acc[1][rg] = e1 * inv;
        acc[2][rg] = e2 * inv; acc[3][rg] = e3 * inv;
    }

    // Column sums for W: per lane partial over its 4 rows, reduce across quads.
#pragma unroll
    for (int nt = 0; nt < 4; nt++) {
        float cs = acc[nt][0] + acc[nt][1] + acc[nt][2] + acc[nt][3];
        cs += __shfl_xor(cs, 16);
        cs += __shfl_xor(cs, 32);
        if (quad == 0) Wtmp[w * 64 + nt * 16 + c] = cs;
    }

    // P -> LDS as bf16 (row = w*16+quad*4+rg, col = nt*16+c)
#pragma unroll
    for (int nt = 0; nt < 4; nt++)
#pragma unroll
        for (int rg = 0; rg < 4; rg++)
            Ph[w * 16 + quad * 4 + rg][nt * 16 + c] = f2bf(acc[nt][rg]);

    __syncthreads();

    if (tid < 64) {
        float s = Wtmp[tid] + Wtmp[64 + tid] + Wtmp[128 + tid] + Wtmp[192 + tid];
        Wpart[((size_t)b * Nc + i) * Tc + tid] = s;   // private slot, no atomics
    }

    // ---- Phase B: out = P(64x64) @ M(64x256), bf16 MFMA, K=64 ----
    v8s pa0 = *(const v8s*)&Ph[w * 16 + c][quad * 8];
    v8s pa1 = *(const v8s*)&Ph[w * 16 + c][32 + quad * 8];

    for (int h0 = 0; h0 < Hc; h0 += 64) {
        // stage MT chunk (64h x 64t bf16) into Xh (Phase A done with it)
#pragma unroll
        for (int rep = 0; rep < 2; rep++) {
            int idx = rep * 256 + tid;
            int row = idx >> 3, c8 = idx & 7;
            *(uint4*)&Xh[row][c8 * 8] = *(const uint4*)(MTg + (size_t)(h0 + row) * Tc + c8 * 8);
        }
        __syncthreads();

        v4f oc[4];
#pragma unroll
        for (int ht = 0; ht < 4; ht++)
#pragma unroll
            for (int rg = 0; rg < 4; rg++) oc[ht][rg] = 0.f;

#pragma unroll
        for (int ht = 0; ht < 4; ht++) {
            v8s b0 = *(const v8s*)&Xh[ht * 16 + c][quad * 8];
            v8s b1 = *(const v8s*)&Xh[ht * 16 + c][32 + quad * 8];
            oc[ht] = __builtin_amdgcn_mfma_f32_16x16x32_bf16(pa0, b0, oc[ht], 0, 0, 0);
            oc[ht] = __builtin_amdgcn_mfma_f32_16x16x32_bf16(pa1, b1, oc[ht], 0, 0, 0);
        }

        float* ob = out + ((size_t)b * NTc + q0 + w * 16 + quad * 4) * Hc + h0 + c;
#pragma unroll
        for (int ht = 0; ht < 4; ht++)
#pragma unroll
            for (int rg = 0; rg < 4; rg++)
                ob[(size_t)rg * Hc + ht * 16] = oc[ht][rg];

        __syncthreads();   // before overwriting Xh next chunk
    }
}

// ---------------------------------------------------------------------------
// W[b,i,t] = (1/16) * sum_i' Wpart[b,i',t]  (independent of i)
// ---------------------------------------------------------------------------
__global__ __launch_bounds__(256) void wexp_kernel(const float* __restrict__ Wpart,
                                                   float* __restrict__ Wout) {
    int idx = blockIdx.x * 256 + threadIdx.x;   // over B*N*T = 32768
    int b = idx >> 10;
    int t = idx & 63;
    const float* wp = Wpart + (size_t)b * Nc * Tc + t;
    float s = 0.f;
#pragma unroll
    for (int ip = 0; ip < Nc; ip++) s += wp[ip * Tc];
    Wout[idx] = s * (1.0f / 16.0f);
}

// ---------------------------------------------------------------------------
extern "C" void kernel_launch(void* const* d_in, const int* in_sizes, int n_in,
                              void* d_out, int out_size, void* d_ws, size_t ws_size,
                              hipStream_t stream) {
    const float* node  = (const float*)d_in[0];   // (B,T,H)
    const float* neigh = (const float*)d_in[1];   // (B,N,T,H)
    const int*   nbr   = (const int*)d_in[2];     // (B,) int32/int64 (detected)

    float* out = (float*)d_out;                   // (B,NT,H) then W (B,N,T)

    u16*   MTw   = (u16*)d_ws;                              // [B][H][T] bf16 mean^T
    float* Wpart = (float*)(MTw + (size_t)Bc * Hc * Tc);    // [B][N][T] fp32 partials

    prep_kernel <<<256, 256, 0, stream>>>(neigh, MTw);
    fused_kernel<<<512, 256, 0, stream>>>(neigh, node, nbr, MTw, out, Wpart);
    wexp_kernel <<<128, 256, 0, stream>>>(Wpart, out + (size_t)Bc * NTc * Hc);
}